// Round 3
// baseline (2834.799 us; speedup 1.0000x reference)
//
#include <hip/hip_runtime.h>
#include <hip/hip_bf16.h>

#define NN 100000
#define EE 6400000
#define FD 128

// ---- index dtype abstraction (row/col may be int32 or int64) ----
__device__ __forceinline__ int load_idx(const void* p, long long i, int is64) {
  if (is64) return (int)((const long long*)p)[i];
  return ((const int*)p)[i];
}

// flag[0] = 1 if buffer is int64 (high words of first 256 elems all zero)
__global__ void detect64_kernel(const int* __restrict__ rowraw, int* __restrict__ flag) {
  __shared__ int nz;
  if (threadIdx.x == 0) nz = 0;
  __syncthreads();
  int w = rowraw[2 * threadIdx.x + 1];
  if (w != 0) atomicAdd(&nz, 1);
  __syncthreads();
  if (threadIdx.x == 0) flag[0] = (nz == 0) ? 1 : 0;
}

static __device__ __forceinline__ int wave_incl_scan(int v) {
  int lane = threadIdx.x & 63;
#pragma unroll
  for (int off = 1; off < 64; off <<= 1) {
    int u = __shfl_up(v, off, 64);
    if (lane >= off) v += u;
  }
  return v;
}

__global__ void deg_count_kernel(const void* __restrict__ rowp, const float* __restrict__ vals,
                                 float* __restrict__ deg, int* __restrict__ cnt,
                                 const int* __restrict__ flag) {
  int is64 = *flag;
  long long i = (long long)blockIdx.x * blockDim.x + threadIdx.x;
  long long stride = (long long)gridDim.x * blockDim.x;
  for (; i < EE; i += stride) {
    int r = load_idx(rowp, i, is64);
    atomicAdd(&cnt[r], 1);
    atomicAdd(&deg[r], vals[i]);
  }
}

__global__ void dinv_kernel(const float* __restrict__ deg, float* __restrict__ dinv) {
  int i = blockIdx.x * blockDim.x + threadIdx.x;
  if (i < NN) {
    float d = deg[i];
    d = d > 0.f ? d : 1.f;
    dinv[i] = 1.f / sqrtf(d);
  }
}

// single-block CSR offset scan (exclusive), 1024 threads, shfl-based
__global__ void scan_kernel(const int* __restrict__ cnt, int* __restrict__ row_start) {
  __shared__ int wsum[16];
  __shared__ int s_carry;
  int t = threadIdx.x;
  int lane = t & 63, wid = t >> 6;
  if (t == 0) { s_carry = 0; row_start[0] = 0; }
  __syncthreads();
  for (int base = 0; base < NN; base += 1024) {
    int idx = base + t;
    int v = (idx < NN) ? cnt[idx] : 0;
    int incl = wave_incl_scan(v);
    if (lane == 63) wsum[wid] = incl;
    __syncthreads();
    int woff = 0;
    for (int w = 0; w < wid; ++w) woff += wsum[w];
    int carry = s_carry;
    if (idx < NN) row_start[idx + 1] = carry + woff + incl;
    __syncthreads();
    if (t == 1023) s_carry = carry + woff + incl;
    __syncthreads();
  }
}

__global__ void scatter_kernel(const void* __restrict__ rowp, const void* __restrict__ colp,
                               const float* __restrict__ vals, const float* __restrict__ dinv,
                               const int* __restrict__ row_start, int* __restrict__ cursor,
                               int* __restrict__ col_s, float* __restrict__ nval_s,
                               const int* __restrict__ flag) {
  int is64 = *flag;
  long long i = (long long)blockIdx.x * blockDim.x + threadIdx.x;
  long long stride = (long long)gridDim.x * blockDim.x;
  for (; i < EE; i += stride) {
    int r = load_idx(rowp, i, is64);
    int c = load_idx(colp, i, is64);
    int pos = row_start[r] + atomicAdd(&cursor[r], 1);
    col_s[pos] = c;
    nval_s[pos] = vals[i] * dinv[r] * dinv[c];
  }
}

// 1 wave per row; lane owns features (2*lane, 2*lane+1) as float2.
// MODE 0: acc = x + s (layer 1); MODE 1: acc += s (layers 2,3)
template <int MODE>
__global__ void spmm_kernel(const int* __restrict__ row_start, const int* __restrict__ col_s,
                            const float* __restrict__ nval_s, const float* __restrict__ h_in,
                            float* __restrict__ h_out, float* __restrict__ acc,
                            const float* __restrict__ xin) {
  int lane = threadIdx.x & 63;
  int wid = threadIdx.x >> 6;
  int r = blockIdx.x * 2 + wid;
  const float2* __restrict__ h2 = (const float2*)h_in;
  int beg = row_start[r], end = row_start[r + 1];
  float sx = 0.f, sy = 0.f;
  for (int e0 = beg; e0 < end; e0 += 64) {
    int rem = end - e0;
    int cc = 0;
    float ww = 0.f;
    if (lane < rem) {
      cc = col_s[e0 + lane];
      ww = nval_s[e0 + lane];
    }
    int lim = rem < 64 ? rem : 64;
#pragma unroll 4
    for (int k = 0; k < lim; ++k) {
      int c = __shfl(cc, k, 64);
      float w = __shfl(ww, k, 64);
      float2 v = h2[(size_t)c * 64 + lane];
      sx = fmaf(w, v.x, sx);
      sy = fmaf(w, v.y, sy);
    }
  }
  size_t o = (size_t)r * 64 + lane;
  float2* ho = (float2*)h_out;
  ho[o] = make_float2(sx, sy);
  float2* acc2 = (float2*)acc;
  float2 a;
  if (MODE == 0) {
    const float2* x2 = (const float2*)xin;
    a = x2[o];
  } else {
    a = acc2[o];
  }
  a.x += sx;
  a.y += sy;
  acc2[o] = a;
}

// out = normalize((acc/4) @ W + b) * 0.1, stored as fp32 rounded through fp16
// (reference does .astype(float16); harness buffer is float32 since output
//  dtype is float16, not bfloat16).
__global__ void out_kernel(const float* __restrict__ acc, const float* __restrict__ W,
                           const float* __restrict__ bias, float* __restrict__ out) {
  __shared__ float Ws[FD * FD];
  __shared__ float es[4 * FD];
  __shared__ float red[2][4];
  int t = threadIdx.x;
  int lane = t & 63, wid = t >> 6;
  for (int i = t; i < FD * FD; i += 128) Ws[i] = W[i];
  float bt = bias[t];
  __syncthreads();
  int r0 = blockIdx.x * 32;
  for (int rr = 0; rr < 32; rr += 4) {
    for (int i = t; i < 4 * FD; i += 128) {
      int rrow = r0 + rr + (i >> 7);
      es[i] = acc[(size_t)rrow * FD + (i & 127)] * 0.25f;
    }
    __syncthreads();
    float y0 = bt, y1 = bt, y2 = bt, y3 = bt;
#pragma unroll 8
    for (int k = 0; k < FD; ++k) {
      float w = Ws[k * FD + t];
      y0 = fmaf(es[k], w, y0);
      y1 = fmaf(es[FD + k], w, y1);
      y2 = fmaf(es[2 * FD + k], w, y2);
      y3 = fmaf(es[3 * FD + k], w, y3);
    }
    float n0 = y0 * y0, n1 = y1 * y1, n2 = y2 * y2, n3 = y3 * y3;
#pragma unroll
    for (int off = 1; off < 64; off <<= 1) {
      n0 += __shfl_xor(n0, off, 64);
      n1 += __shfl_xor(n1, off, 64);
      n2 += __shfl_xor(n2, off, 64);
      n3 += __shfl_xor(n3, off, 64);
    }
    if (lane == 0) {
      red[wid][0] = n0;
      red[wid][1] = n1;
      red[wid][2] = n2;
      red[wid][3] = n3;
    }
    __syncthreads();
    float s0 = 0.1f / fmaxf(sqrtf(red[0][0] + red[1][0]), 1e-12f);
    float s1 = 0.1f / fmaxf(sqrtf(red[0][1] + red[1][1]), 1e-12f);
    float s2 = 0.1f / fmaxf(sqrtf(red[0][2] + red[1][2]), 1e-12f);
    float s3 = 0.1f / fmaxf(sqrtf(red[0][3] + red[1][3]), 1e-12f);
    size_t ob = (size_t)(r0 + rr) * FD + t;
    out[ob] = (float)(_Float16)(y0 * s0);
    out[ob + FD] = (float)(_Float16)(y1 * s1);
    out[ob + 2 * FD] = (float)(_Float16)(y2 * s2);
    out[ob + 3 * FD] = (float)(_Float16)(y3 * s3);
    __syncthreads();
  }
}

extern "C" void kernel_launch(void* const* d_in, const int* in_sizes, int n_in,
                              void* d_out, int out_size, void* d_ws, size_t ws_size,
                              hipStream_t stream) {
  const void* rowp = d_in[0];
  const void* colp = d_in[1];
  const float* vals = (const float*)d_in[2];
  const float* x = (const float*)d_in[3];
  const float* W = (const float*)d_in[4];
  const float* bias = (const float*)d_in[5];
  float* out = (float*)d_out;

  char* ws = (char*)d_ws;
  size_t off = 0;
  auto alloc = [&](size_t bytes) {
    void* p = ws + off;
    off = (off + bytes + 511) & ~(size_t)511;
    return p;
  };
  float* deg = (float*)alloc(NN * 4);
  float* dinv = (float*)alloc(NN * 4);
  int* cnt = (int*)alloc(NN * 4);
  int* cursor = (int*)alloc(NN * 4);
  int* rs = (int*)alloc((NN + 1) * 4);
  int* flag = (int*)alloc(64);
  float* hA = (float*)alloc((size_t)NN * FD * 4);
  float* hB = (float*)alloc((size_t)NN * FD * 4);
  float* acc = (float*)alloc((size_t)NN * FD * 4);
  int* col_s = (int*)alloc((size_t)EE * 4);
  float* nval_s = (float*)alloc((size_t)EE * 4);

  hipMemsetAsync(deg, 0, NN * 4, stream);
  hipMemsetAsync(cnt, 0, NN * 4, stream);
  hipMemsetAsync(cursor, 0, NN * 4, stream);

  detect64_kernel<<<1, 256, 0, stream>>>((const int*)rowp, flag);
  deg_count_kernel<<<1024, 256, 0, stream>>>(rowp, vals, deg, cnt, flag);
  dinv_kernel<<<(NN + 255) / 256, 256, 0, stream>>>(deg, dinv);
  scan_kernel<<<1, 1024, 0, stream>>>(cnt, rs);
  scatter_kernel<<<1024, 256, 0, stream>>>(rowp, colp, vals, dinv, rs, cursor, col_s, nval_s, flag);

  spmm_kernel<0><<<NN / 2, 128, 0, stream>>>(rs, col_s, nval_s, x, hA, acc, x);
  spmm_kernel<1><<<NN / 2, 128, 0, stream>>>(rs, col_s, nval_s, hA, hB, acc, nullptr);
  spmm_kernel<1><<<NN / 2, 128, 0, stream>>>(rs, col_s, nval_s, hB, hA, acc, nullptr);

  out_kernel<<<NN / 32, 128, 0, stream>>>(acc, W, bias, out);
}

// Round 4
// 2347.025 us; speedup vs baseline: 1.2078x; 1.2078x over previous
//
#include <hip/hip_runtime.h>
#include <hip/hip_bf16.h>

#define NN 100000
#define EE 6400000
#define FD 128

// ---- index dtype abstraction (row/col may be int32 or int64) ----
__device__ __forceinline__ int load_idx(const void* p, long long i, int is64) {
  if (is64) return (int)((const long long*)p)[i];
  return ((const int*)p)[i];
}

// flag[0] = 1 if buffer is int64 (high words of first 256 elems all zero)
__global__ void detect64_kernel(const int* __restrict__ rowraw, int* __restrict__ flag) {
  __shared__ int nz;
  if (threadIdx.x == 0) nz = 0;
  __syncthreads();
  int w = rowraw[2 * threadIdx.x + 1];
  if (w != 0) atomicAdd(&nz, 1);
  __syncthreads();
  if (threadIdx.x == 0) flag[0] = (nz == 0) ? 1 : 0;
}

static __device__ __forceinline__ int wave_incl_scan(int v) {
  int lane = threadIdx.x & 63;
#pragma unroll
  for (int off = 1; off < 64; off <<= 1) {
    int u = __shfl_up(v, off, 64);
    if (lane >= off) v += u;
  }
  return v;
}

// int-only histogram of row ids
__global__ void hist_kernel(const void* __restrict__ rowp, int* __restrict__ cnt,
                            const int* __restrict__ flag) {
  int is64 = *flag;
  long long i = (long long)blockIdx.x * blockDim.x + threadIdx.x;
  long long stride = (long long)gridDim.x * blockDim.x;
  for (; i < EE; i += stride) {
    int r = load_idx(rowp, i, is64);
    atomicAdd(&cnt[r], 1);
  }
}

// single-block exclusive scan: row_start[0..N], cursor[i] = row_start[i]
__global__ void scan_kernel(const int* __restrict__ cnt, int* __restrict__ row_start,
                            int* __restrict__ cursor) {
  __shared__ int wsum[16];
  __shared__ int s_carry;
  int t = threadIdx.x;
  int lane = t & 63, wid = t >> 6;
  if (t == 0) { s_carry = 0; row_start[0] = 0; }
  __syncthreads();
  for (int base = 0; base < NN; base += 1024) {
    int idx = base + t;
    int v = (idx < NN) ? cnt[idx] : 0;
    int incl = wave_incl_scan(v);
    if (lane == 63) wsum[wid] = incl;
    __syncthreads();
    int woff = 0;
    for (int w = 0; w < wid; ++w) woff += wsum[w];
    int carry = s_carry;
    if (idx < NN) {
      row_start[idx + 1] = carry + woff + incl;
      cursor[idx] = carry + woff + incl - v;  // exclusive
    }
    __syncthreads();
    if (t == 1023) s_carry = carry + woff + incl;
    __syncthreads();
  }
}

// counting-sort scatter: one packed 8B {col, raw val} store per edge
__global__ void scatter_kernel(const void* __restrict__ rowp, const void* __restrict__ colp,
                               const float* __restrict__ vals, int* __restrict__ cursor,
                               int2* __restrict__ edges, const int* __restrict__ flag) {
  int is64 = *flag;
  long long i = (long long)blockIdx.x * blockDim.x + threadIdx.x;
  long long stride = (long long)gridDim.x * blockDim.x;
  for (; i < EE; i += stride) {
    int r = load_idx(rowp, i, is64);
    int c = load_idx(colp, i, is64);
    int pos = atomicAdd(&cursor[r], 1);
    int2 e;
    e.x = c;
    e.y = __float_as_int(vals[i]);
    edges[pos] = e;
  }
}

// wave per row: deg = segment sum of raw vals; dinv = 1/sqrt(max(deg,1-if-zero))
__global__ void degdinv_kernel(const int* __restrict__ rs, const int2* __restrict__ edges,
                               float* __restrict__ dinv) {
  int lane = threadIdx.x & 63;
  int gid = blockIdx.x * (blockDim.x >> 6) + (threadIdx.x >> 6);
  if (gid >= NN) return;
  int beg = rs[gid], end = rs[gid + 1];
  float s = 0.f;
  for (int e = beg + lane; e < end; e += 64) s += __int_as_float(edges[e].y);
#pragma unroll
  for (int off = 1; off < 64; off <<= 1) s += __shfl_xor(s, off, 64);
  if (lane == 0) {
    float d = s > 0.f ? s : 1.f;
    dinv[gid] = 1.f / sqrtf(d);
  }
}

// 1 wave per row; lane owns features (2*lane, 2*lane+1) as float2.
// MODE 0 (layer 1): edge vals are RAW -> normalize with dinv, write nval back
//                   in-place (coalesced), acc = x + s.
// MODE 1 (layers 2,3): edge vals already normalized, acc += s.
template <int MODE>
__global__ void spmm_kernel(const int* __restrict__ row_start, int2* __restrict__ edges,
                            const float* __restrict__ dinv, const float* __restrict__ h_in,
                            float* __restrict__ h_out, float* __restrict__ acc,
                            const float* __restrict__ xin) {
  int lane = threadIdx.x & 63;
  int wid = threadIdx.x >> 6;
  int r = blockIdx.x * 2 + wid;
  const float2* __restrict__ h2 = (const float2*)h_in;
  int beg = row_start[r], end = row_start[r + 1];
  float dr = (MODE == 0) ? dinv[r] : 0.f;
  float sx = 0.f, sy = 0.f;
  for (int e0 = beg; e0 < end; e0 += 64) {
    int rem = end - e0;
    int cc = 0;
    float ww = 0.f;
    if (lane < rem) {
      int2 e = edges[e0 + lane];
      cc = e.x;
      ww = __int_as_float(e.y);
    }
    if (MODE == 0) {
      ww *= dr * dinv[cc];  // inactive lanes: ww stays 0
      if (lane < rem) ((float*)&edges[e0 + lane])[1] = ww;
    }
    int lim = rem < 64 ? rem : 64;
#pragma unroll 4
    for (int k = 0; k < lim; ++k) {
      int c = __shfl(cc, k, 64);
      float w = __shfl(ww, k, 64);
      float2 v = h2[(size_t)c * 64 + lane];
      sx = fmaf(w, v.x, sx);
      sy = fmaf(w, v.y, sy);
    }
  }
  size_t o = (size_t)r * 64 + lane;
  float2* ho = (float2*)h_out;
  ho[o] = make_float2(sx, sy);
  float2* acc2 = (float2*)acc;
  float2 a;
  if (MODE == 0) {
    const float2* x2 = (const float2*)xin;
    a = x2[o];
  } else {
    a = acc2[o];
  }
  a.x += sx;
  a.y += sy;
  acc2[o] = a;
}

// out = normalize((acc/4) @ W + b) * 0.1, fp32 rounded through fp16
__global__ void out_kernel(const float* __restrict__ acc, const float* __restrict__ W,
                           const float* __restrict__ bias, float* __restrict__ out) {
  __shared__ float Ws[FD * FD];
  __shared__ float es[4 * FD];
  __shared__ float red[2][4];
  int t = threadIdx.x;
  int lane = t & 63, wid = t >> 6;
  for (int i = t; i < FD * FD; i += 128) Ws[i] = W[i];
  float bt = bias[t];
  __syncthreads();
  int r0 = blockIdx.x * 32;
  for (int rr = 0; rr < 32; rr += 4) {
    for (int i = t; i < 4 * FD; i += 128) {
      int rrow = r0 + rr + (i >> 7);
      es[i] = acc[(size_t)rrow * FD + (i & 127)] * 0.25f;
    }
    __syncthreads();
    float y0 = bt, y1 = bt, y2 = bt, y3 = bt;
#pragma unroll 8
    for (int k = 0; k < FD; ++k) {
      float w = Ws[k * FD + t];
      y0 = fmaf(es[k], w, y0);
      y1 = fmaf(es[FD + k], w, y1);
      y2 = fmaf(es[2 * FD + k], w, y2);
      y3 = fmaf(es[3 * FD + k], w, y3);
    }
    float n0 = y0 * y0, n1 = y1 * y1, n2 = y2 * y2, n3 = y3 * y3;
#pragma unroll
    for (int off = 1; off < 64; off <<= 1) {
      n0 += __shfl_xor(n0, off, 64);
      n1 += __shfl_xor(n1, off, 64);
      n2 += __shfl_xor(n2, off, 64);
      n3 += __shfl_xor(n3, off, 64);
    }
    if (lane == 0) {
      red[wid][0] = n0;
      red[wid][1] = n1;
      red[wid][2] = n2;
      red[wid][3] = n3;
    }
    __syncthreads();
    float s0 = 0.1f / fmaxf(sqrtf(red[0][0] + red[1][0]), 1e-12f);
    float s1 = 0.1f / fmaxf(sqrtf(red[0][1] + red[1][1]), 1e-12f);
    float s2 = 0.1f / fmaxf(sqrtf(red[0][2] + red[1][2]), 1e-12f);
    float s3 = 0.1f / fmaxf(sqrtf(red[0][3] + red[1][3]), 1e-12f);
    size_t ob = (size_t)(r0 + rr) * FD + t;
    out[ob] = (float)(_Float16)(y0 * s0);
    out[ob + FD] = (float)(_Float16)(y1 * s1);
    out[ob + 2 * FD] = (float)(_Float16)(y2 * s2);
    out[ob + 3 * FD] = (float)(_Float16)(y3 * s3);
    __syncthreads();
  }
}

extern "C" void kernel_launch(void* const* d_in, const int* in_sizes, int n_in,
                              void* d_out, int out_size, void* d_ws, size_t ws_size,
                              hipStream_t stream) {
  const void* rowp = d_in[0];
  const void* colp = d_in[1];
  const float* vals = (const float*)d_in[2];
  const float* x = (const float*)d_in[3];
  const float* W = (const float*)d_in[4];
  const float* bias = (const float*)d_in[5];
  float* out = (float*)d_out;

  char* ws = (char*)d_ws;
  size_t off = 0;
  auto alloc = [&](size_t bytes) {
    void* p = ws + off;
    off = (off + bytes + 511) & ~(size_t)511;
    return p;
  };
  float* dinv = (float*)alloc(NN * 4);
  int* cnt = (int*)alloc(NN * 4);
  int* cursor = (int*)alloc(NN * 4);
  int* rs = (int*)alloc((NN + 1) * 4);
  int* flag = (int*)alloc(64);
  float* hA = (float*)alloc((size_t)NN * FD * 4);
  float* hB = (float*)alloc((size_t)NN * FD * 4);
  float* acc = (float*)alloc((size_t)NN * FD * 4);
  int2* edges = (int2*)alloc((size_t)EE * 8);

  hipMemsetAsync(cnt, 0, NN * 4, stream);

  detect64_kernel<<<1, 256, 0, stream>>>((const int*)rowp, flag);
  hist_kernel<<<2048, 256, 0, stream>>>(rowp, cnt, flag);
  scan_kernel<<<1, 1024, 0, stream>>>(cnt, rs, cursor);
  scatter_kernel<<<2048, 256, 0, stream>>>(rowp, colp, vals, cursor, edges, flag);
  degdinv_kernel<<<(NN + 3) / 4, 256, 0, stream>>>(rs, edges, dinv);

  spmm_kernel<0><<<NN / 2, 128, 0, stream>>>(rs, edges, dinv, x, hA, acc, x);
  spmm_kernel<1><<<NN / 2, 128, 0, stream>>>(rs, edges, dinv, hA, hB, acc, nullptr);
  spmm_kernel<1><<<NN / 2, 128, 0, stream>>>(rs, edges, dinv, hB, hA, acc, nullptr);

  out_kernel<<<NN / 32, 128, 0, stream>>>(acc, W, bias, out);
}

// Round 5
// 2040.330 us; speedup vs baseline: 1.3894x; 1.1503x over previous
//
#include <hip/hip_runtime.h>
#include <hip/hip_bf16.h>

#define NN 100000
#define EE 6400000
#define FD 128

typedef unsigned int uint32;
typedef unsigned short ushort16;

__device__ __forceinline__ float bf2f(ushort16 u) {
  return __uint_as_float(((uint32)u) << 16);
}
__device__ __forceinline__ ushort16 f2bf(float f) {
  uint32 u = __float_as_uint(f);
  u += 0x7fff + ((u >> 16) & 1);  // round-to-nearest-even (finite inputs)
  return (ushort16)(u >> 16);
}

// ---- index dtype abstraction (row/col may be int32 or int64) ----
__device__ __forceinline__ int load_idx(const void* p, long long i, int is64) {
  if (is64) return (int)((const long long*)p)[i];
  return ((const int*)p)[i];
}

// flag[0] = 1 if buffer is int64 (high words of first 256 elems all zero)
__global__ void detect64_kernel(const int* __restrict__ rowraw, int* __restrict__ flag) {
  __shared__ int nz;
  if (threadIdx.x == 0) nz = 0;
  __syncthreads();
  int w = rowraw[2 * threadIdx.x + 1];
  if (w != 0) atomicAdd(&nz, 1);
  __syncthreads();
  if (threadIdx.x == 0) flag[0] = (nz == 0) ? 1 : 0;
}

static __device__ __forceinline__ int wave_incl_scan(int v) {
  int lane = threadIdx.x & 63;
#pragma unroll
  for (int off = 1; off < 64; off <<= 1) {
    int u = __shfl_up(v, off, 64);
    if (lane >= off) v += u;
  }
  return v;
}

// int-only histogram of row ids
__global__ void hist_kernel(const void* __restrict__ rowp, int* __restrict__ cnt,
                            const int* __restrict__ flag) {
  int is64 = *flag;
  long long i = (long long)blockIdx.x * blockDim.x + threadIdx.x;
  long long stride = (long long)gridDim.x * blockDim.x;
  for (; i < EE; i += stride) {
    int r = load_idx(rowp, i, is64);
    atomicAdd(&cnt[r], 1);
  }
}

// single-block exclusive scan: row_start[0..N], cursor[i] = row_start[i]
__global__ void scan_kernel(const int* __restrict__ cnt, int* __restrict__ row_start,
                            int* __restrict__ cursor) {
  __shared__ int wsum[16];
  __shared__ int s_carry;
  int t = threadIdx.x;
  int lane = t & 63, wid = t >> 6;
  if (t == 0) { s_carry = 0; row_start[0] = 0; }
  __syncthreads();
  for (int base = 0; base < NN; base += 1024) {
    int idx = base + t;
    int v = (idx < NN) ? cnt[idx] : 0;
    int incl = wave_incl_scan(v);
    if (lane == 63) wsum[wid] = incl;
    __syncthreads();
    int woff = 0;
    for (int w = 0; w < wid; ++w) woff += wsum[w];
    int carry = s_carry;
    if (idx < NN) {
      row_start[idx + 1] = carry + woff + incl;
      cursor[idx] = carry + woff + incl - v;  // exclusive
    }
    __syncthreads();
    if (t == 1023) s_carry = carry + woff + incl;
    __syncthreads();
  }
}

// counting-sort scatter: one packed 8B {col, raw val} store per edge
__global__ void scatter_kernel(const void* __restrict__ rowp, const void* __restrict__ colp,
                               const float* __restrict__ vals, int* __restrict__ cursor,
                               int2* __restrict__ edges, const int* __restrict__ flag) {
  int is64 = *flag;
  long long i = (long long)blockIdx.x * blockDim.x + threadIdx.x;
  long long stride = (long long)gridDim.x * blockDim.x;
  for (; i < EE; i += stride) {
    int r = load_idx(rowp, i, is64);
    int c = load_idx(colp, i, is64);
    int pos = atomicAdd(&cursor[r], 1);
    int2 e;
    e.x = c;
    e.y = __float_as_int(vals[i]);
    edges[pos] = e;
  }
}

// wave per row: deg = segment sum of raw vals; dinv = 1/sqrt
__global__ void degdinv_kernel(const int* __restrict__ rs, const int2* __restrict__ edges,
                               float* __restrict__ dinv) {
  int lane = threadIdx.x & 63;
  int gid = blockIdx.x * (blockDim.x >> 6) + (threadIdx.x >> 6);
  if (gid >= NN) return;
  int beg = rs[gid], end = rs[gid + 1];
  float s = 0.f;
  for (int e = beg + lane; e < end; e += 64) s += __int_as_float(edges[e].y);
#pragma unroll
  for (int off = 1; off < 64; off <<= 1) s += __shfl_xor(s, off, 64);
  if (lane == 0) {
    float d = s > 0.f ? s : 1.f;
    dinv[gid] = 1.f / sqrtf(d);
  }
}

// x (fp32) -> bf16x2 packed
__global__ void xcvt_kernel(const float* __restrict__ x, uint32* __restrict__ hx) {
  int i = blockIdx.x * blockDim.x + threadIdx.x;
  if (i < NN * 64) {
    float2 v = ((const float2*)x)[i];
    hx[i] = ((uint32)f2bf(v.y) << 16) | f2bf(v.x);
  }
}

// 1 wave per row; lane owns features (2*lane, 2*lane+1) packed as bf16x2 (4B).
// MODE 0 (layer 1): edge vals RAW -> normalize with dinv, write nval back.
// MODE 1 (layers 2,3): edge vals already normalized.
template <int MODE>
__global__ void spmm_kernel(const int* __restrict__ row_start, int2* __restrict__ edges,
                            const float* __restrict__ dinv, const uint32* __restrict__ h_in,
                            uint32* __restrict__ h_out) {
  int lane = threadIdx.x & 63;
  int wid = threadIdx.x >> 6;
  int r = blockIdx.x * 2 + wid;
  int beg = row_start[r], end = row_start[r + 1];
  float dr = (MODE == 0) ? dinv[r] : 0.f;
  float sx = 0.f, sy = 0.f;
  for (int e0 = beg; e0 < end; e0 += 64) {
    int rem = end - e0;
    int cc = 0;
    float ww = 0.f;
    if (lane < rem) {
      int2 e = edges[e0 + lane];
      cc = e.x;
      ww = __int_as_float(e.y);
    }
    if (MODE == 0) {
      ww *= dr * dinv[cc];  // inactive lanes keep ww == 0
      if (lane < rem) ((float*)&edges[e0 + lane])[1] = ww;
    }
    int lim = rem < 64 ? rem : 64;
#pragma unroll 4
    for (int k = 0; k < lim; ++k) {
      int c = __shfl(cc, k, 64);
      float w = __shfl(ww, k, 64);
      uint32 pv = h_in[(uint32)c * 64 + lane];
      sx = fmaf(w, bf2f((ushort16)(pv & 0xffff)), sx);
      sy = fmaf(w, bf2f((ushort16)(pv >> 16)), sy);
    }
  }
  uint32 o = (uint32)r * 64 + lane;
  h_out[o] = ((uint32)f2bf(sy) << 16) | f2bf(sx);
}

// out = normalize(((x+h1+h2+h3)/4) @ W + b) * 0.1, fp32 rounded through fp16
__global__ void out_kernel(const float* __restrict__ x, const ushort16* __restrict__ h1,
                           const ushort16* __restrict__ h2, const ushort16* __restrict__ h3,
                           const float* __restrict__ W, const float* __restrict__ bias,
                           float* __restrict__ out) {
  __shared__ float Ws[FD * FD];
  __shared__ float es[4 * FD];
  __shared__ float red[2][4];
  int t = threadIdx.x;
  int lane = t & 63, wid = t >> 6;
  for (int i = t; i < FD * FD; i += 128) Ws[i] = W[i];
  float bt = bias[t];
  __syncthreads();
  int r0 = blockIdx.x * 32;
  for (int rr = 0; rr < 32; rr += 4) {
    for (int i = t; i < 4 * FD; i += 128) {
      int rrow = r0 + rr + (i >> 7);
      size_t base = (size_t)rrow * FD + (i & 127);
      float v = x[base] + bf2f(h1[base]) + bf2f(h2[base]) + bf2f(h3[base]);
      es[i] = v * 0.25f;
    }
    __syncthreads();
    float y0 = bt, y1 = bt, y2 = bt, y3 = bt;
#pragma unroll 8
    for (int k = 0; k < FD; ++k) {
      float w = Ws[k * FD + t];
      y0 = fmaf(es[k], w, y0);
      y1 = fmaf(es[FD + k], w, y1);
      y2 = fmaf(es[2 * FD + k], w, y2);
      y3 = fmaf(es[3 * FD + k], w, y3);
    }
    float n0 = y0 * y0, n1 = y1 * y1, n2 = y2 * y2, n3 = y3 * y3;
#pragma unroll
    for (int off = 1; off < 64; off <<= 1) {
      n0 += __shfl_xor(n0, off, 64);
      n1 += __shfl_xor(n1, off, 64);
      n2 += __shfl_xor(n2, off, 64);
      n3 += __shfl_xor(n3, off, 64);
    }
    if (lane == 0) {
      red[wid][0] = n0;
      red[wid][1] = n1;
      red[wid][2] = n2;
      red[wid][3] = n3;
    }
    __syncthreads();
    float s0 = 0.1f / fmaxf(sqrtf(red[0][0] + red[1][0]), 1e-12f);
    float s1 = 0.1f / fmaxf(sqrtf(red[0][1] + red[1][1]), 1e-12f);
    float s2 = 0.1f / fmaxf(sqrtf(red[0][2] + red[1][2]), 1e-12f);
    float s3 = 0.1f / fmaxf(sqrtf(red[0][3] + red[1][3]), 1e-12f);
    size_t ob = (size_t)(r0 + rr) * FD + t;
    out[ob] = (float)(_Float16)(y0 * s0);
    out[ob + FD] = (float)(_Float16)(y1 * s1);
    out[ob + 2 * FD] = (float)(_Float16)(y2 * s2);
    out[ob + 3 * FD] = (float)(_Float16)(y3 * s3);
    __syncthreads();
  }
}

extern "C" void kernel_launch(void* const* d_in, const int* in_sizes, int n_in,
                              void* d_out, int out_size, void* d_ws, size_t ws_size,
                              hipStream_t stream) {
  const void* rowp = d_in[0];
  const void* colp = d_in[1];
  const float* vals = (const float*)d_in[2];
  const float* x = (const float*)d_in[3];
  const float* W = (const float*)d_in[4];
  const float* bias = (const float*)d_in[5];
  float* out = (float*)d_out;

  char* ws = (char*)d_ws;
  size_t off = 0;
  auto alloc = [&](size_t bytes) {
    void* p = ws + off;
    off = (off + bytes + 511) & ~(size_t)511;
    return p;
  };
  float* dinv = (float*)alloc(NN * 4);
  int* cnt = (int*)alloc(NN * 4);
  int* cursor = (int*)alloc(NN * 4);
  int* rs = (int*)alloc((NN + 1) * 4);
  int* flag = (int*)alloc(64);
  uint32* hX = (uint32*)alloc((size_t)NN * 64 * 4);
  uint32* h1 = (uint32*)alloc((size_t)NN * 64 * 4);
  uint32* h2 = (uint32*)alloc((size_t)NN * 64 * 4);
  uint32* h3 = (uint32*)alloc((size_t)NN * 64 * 4);
  int2* edges = (int2*)alloc((size_t)EE * 8);

  hipMemsetAsync(cnt, 0, NN * 4, stream);

  detect64_kernel<<<1, 256, 0, stream>>>((const int*)rowp, flag);
  hist_kernel<<<2048, 256, 0, stream>>>(rowp, cnt, flag);
  scan_kernel<<<1, 1024, 0, stream>>>(cnt, rs, cursor);
  scatter_kernel<<<2048, 256, 0, stream>>>(rowp, colp, vals, cursor, edges, flag);
  degdinv_kernel<<<(NN + 3) / 4, 256, 0, stream>>>(rs, edges, dinv);
  xcvt_kernel<<<(NN * 64 + 255) / 256, 256, 0, stream>>>(x, hX);

  spmm_kernel<0><<<NN / 2, 128, 0, stream>>>(rs, edges, dinv, hX, h1);
  spmm_kernel<1><<<NN / 2, 128, 0, stream>>>(rs, edges, dinv, h1, h2);
  spmm_kernel<1><<<NN / 2, 128, 0, stream>>>(rs, edges, dinv, h2, h3);

  out_kernel<<<NN / 32, 128, 0, stream>>>(x, (const ushort16*)h1, (const ushort16*)h2,
                                          (const ushort16*)h3, W, bias, out);
}